// Round 1
// baseline (917.363 us; speedup 1.0000x reference)
//
#include <hip/hip_runtime.h>
#include <math.h>

// SpectralConv1d: B=16, L=4096, H=8, E=Eo=M=64.
// out[b,h,o,t] = (1/L) * sum_f c_f * Re( (sum_e X[b,h,e,f]*W[h,e,o,f]) * e^{+2pi i f t/L} )
// X[b,h,e,f]   = sum_t q[b,t,h,e] * e^{-2pi i f t / L},  f < 64, c_0=1, c_f=2.
//
// ws layout (floats):
//   TW1 [4096 t][64 f] float2 = (cos th, -sin th), th = 2pi*((f*t)&4095)/4096
//   TW2 [4096 t][64 f] float2 = (sc*cos th, -sc*sin th), sc = (f?2:1)/4096
//   X   [128 bh][64 e][64 f] float2
//   Y   [128 bh][64 o][64 f] float2
#define TW1_OFF 0
#define TW2_OFF 524288
#define X_OFF   1048576
#define Y_OFF   2097152

__global__ __launch_bounds__(256) void k_twiddle(float* __restrict__ ws) {
    const int idx = blockIdx.x * 256 + threadIdx.x;   // idx = t*64 + f
    const int t = idx >> 6, f = idx & 63;
    const int m = (f * t) & 4095;
    const float th = (float)m * 1.53398078788564123e-3f;  // 2*pi/4096
    float s, c;
    sincosf(th, &s, &c);
    float2* tw1 = (float2*)(ws + TW1_OFF);
    float2* tw2 = (float2*)(ws + TW2_OFF);
    tw1[idx] = make_float2(c, -s);
    const float sc = (f == 0 ? 1.0f : 2.0f) * (1.0f / 4096.0f);
    tw2[idx] = make_float2(sc * c, -sc * s);
}

// Stage 1: truncated DFT. Grid 256 = 128 (b,h) x 2 e-halves. Block tile: 32e x 64f, K=4096.
// Thread tile: 2e x 4f complex. te=tid&15 (e spread across lanes -> conflict-free LDS),
// tf=tid>>4 (f group -> LDS broadcast reads).
__global__ __launch_bounds__(256) void k_dft(const float* __restrict__ q,
                                             float* __restrict__ ws) {
    __shared__ float  lds_q[32][32];    // [t-chunk][e-half]
    __shared__ float2 lds_tw[32][64];   // [t-chunk][f]
    const int bid = blockIdx.x;
    const int bh = bid >> 1;
    const int e_base = (bid & 1) * 32;
    const int b = bh >> 3, h = bh & 7;
    const int tid = threadIdx.x;
    const int tf = tid >> 4;            // 0..15 -> f0 = 4*tf
    const int te = tid & 15;            // 0..15 -> e pair
    const int f0 = tf * 4;
    const int s_tt = tid >> 3, s_e4 = (tid & 7) * 4;

    float ar[2][4] = {{0.f, 0.f, 0.f, 0.f}, {0.f, 0.f, 0.f, 0.f}};
    float ai[2][4] = {{0.f, 0.f, 0.f, 0.f}, {0.f, 0.f, 0.f, 0.f}};

    const float2* tw1 = (const float2*)(ws + TW1_OFF);
    for (int t0 = 0; t0 < 4096; t0 += 32) {
        // stage q chunk: 32t x 32e, coalesced float4
        const float4 qv4 = *(const float4*)(q + (((b * 4096 + t0 + s_tt) * 8 + h) * 64 + e_base + s_e4));
        *(float4*)&lds_q[s_tt][s_e4] = qv4;
        // stage twiddle chunk: contiguous 16 KB
        {
            const float4* src = (const float4*)(tw1 + t0 * 64);
            float4* dst = (float4*)&lds_tw[0][0];
            #pragma unroll
            for (int k = 0; k < 4; ++k) dst[tid + k * 256] = src[tid + k * 256];
        }
        __syncthreads();
        #pragma unroll 8
        for (int tt = 0; tt < 32; ++tt) {
            const float2 q2  = *(const float2*)&lds_q[tt][te * 2];
            const float4 csA = *(const float4*)&lds_tw[tt][f0];      // (c0,s0,c1,s1)
            const float4 csB = *(const float4*)&lds_tw[tt][f0 + 2];  // (c2,s2,c3,s3)
            ar[0][0] += q2.x * csA.x; ai[0][0] += q2.x * csA.y;
            ar[0][1] += q2.x * csA.z; ai[0][1] += q2.x * csA.w;
            ar[0][2] += q2.x * csB.x; ai[0][2] += q2.x * csB.y;
            ar[0][3] += q2.x * csB.z; ai[0][3] += q2.x * csB.w;
            ar[1][0] += q2.y * csA.x; ai[1][0] += q2.y * csA.y;
            ar[1][1] += q2.y * csA.z; ai[1][1] += q2.y * csA.w;
            ar[1][2] += q2.y * csB.x; ai[1][2] += q2.y * csB.y;
            ar[1][3] += q2.y * csB.z; ai[1][3] += q2.y * csB.w;
        }
        __syncthreads();
    }
    float2* X = (float2*)(ws + X_OFF);
    #pragma unroll
    for (int i = 0; i < 2; ++i) {
        const int e = e_base + te * 2 + i;
        float2* dstx = X + ((bh * 64 + e) * 64 + f0);
        dstx[0] = make_float2(ar[i][0], ai[i][0]);
        dstx[1] = make_float2(ar[i][1], ai[i][1]);
        dstx[2] = make_float2(ar[i][2], ai[i][2]);
        dstx[3] = make_float2(ar[i][3], ai[i][3]);
    }
}

// Stage 2: mode mix. One block per (b,h); X slice staged in LDS; W streamed (L2/L3 reuse over b).
__global__ __launch_bounds__(256) void k_mix(const float* __restrict__ wr_g,
                                             const float* __restrict__ wi_g,
                                             float* __restrict__ ws) {
    __shared__ float2 lds_x[64][64];    // [e][f]
    const int bh = blockIdx.x;
    const int h = bh & 7;
    const int tid = threadIdx.x;
    const float2* X = (const float2*)(ws + X_OFF) + bh * 4096;
    {
        const float4* src = (const float4*)X;
        float4* dst = (float4*)&lds_x[0][0];
        #pragma unroll
        for (int k = 0; k < 8; ++k) dst[tid + k * 256] = src[tid + k * 256];
    }
    __syncthreads();
    const int f = tid & 63;
    const int orow = tid >> 6;          // 0..3 ; o = 4k + orow
    float accr[16], acci[16];
    #pragma unroll
    for (int k = 0; k < 16; ++k) { accr[k] = 0.f; acci[k] = 0.f; }
    const float* wrp = wr_g + (h * 64 * 64 + orow) * 64 + f;
    const float* wip = wi_g + (h * 64 * 64 + orow) * 64 + f;
    for (int e = 0; e < 64; ++e) {
        const float2 x = lds_x[e][f];
        const float* wre = wrp + e * 4096;
        const float* wie = wip + e * 4096;
        #pragma unroll
        for (int k = 0; k < 16; ++k) {
            const float Wr = wre[k * 256];
            const float Wi = wie[k * 256];
            accr[k] += x.x * Wr - x.y * Wi;
            acci[k] += x.x * Wi + x.y * Wr;
        }
    }
    float2* Y = (float2*)(ws + Y_OFF) + bh * 4096;
    #pragma unroll
    for (int k = 0; k < 16; ++k) {
        const int o = k * 4 + orow;
        Y[o * 64 + f] = make_float2(accr[k], acci[k]);
    }
}

// Stage 3: truncated inverse. Grid 8192 = 128 (b,h) x 64 t-tiles of 64.
// out[t] = sum_f TW2a[t][f]*Yr[o][f] + TW2b[t][f]*Yi[o][f].
// Thread tile: 4t x 4o; o set {oq+16c} so each LDS y-read instr hits all 32 banks
// (row stride 65 float2 == 2 mod 32 floats); w reads are 4-addr broadcast (stride 33).
__global__ __launch_bounds__(256) void k_inv(float* __restrict__ out,
                                             const float* __restrict__ ws) {
    __shared__ float2 lds_y[64][65];    // [o][f], padded
    __shared__ float2 lds_w[64][33];    // [t][f-half], padded
    const int bid = blockIdx.x;
    const int bh = bid >> 6;
    const int tt = bid & 63;
    const int tid = threadIdx.x;
    const float2* Y   = (const float2*)(ws + Y_OFF) + bh * 4096;
    const float2* TW2 = (const float2*)(ws + TW2_OFF) + tt * 64 * 64;
    #pragma unroll
    for (int k = 0; k < 16; ++k) {
        const int i = tid + k * 256;
        lds_y[i >> 6][i & 63] = Y[i];
    }
    const int oq = tid & 15;            // o = oq + 16c
    const int tq = tid >> 4;            // t0 = 4*tq
    const int t0 = tq * 4;
    float acc[4][4];                    // [t][o]
    #pragma unroll
    for (int r = 0; r < 4; ++r)
        #pragma unroll
        for (int c = 0; c < 4; ++c) acc[r][c] = 0.f;

    #pragma unroll
    for (int p = 0; p < 2; ++p) {
        #pragma unroll
        for (int k = 0; k < 8; ++k) {
            const int i = tid + k * 256;          // 0..2047
            const int row = i >> 5, col = i & 31;
            lds_w[row][col] = TW2[row * 64 + p * 32 + col];
        }
        __syncthreads();
        #pragma unroll 4
        for (int fl = 0; fl < 32; ++fl) {
            const int f = p * 32 + fl;
            float2 wv[4], yv[4];
            #pragma unroll
            for (int r = 0; r < 4; ++r) wv[r] = lds_w[t0 + r][fl];
            #pragma unroll
            for (int c = 0; c < 4; ++c) yv[c] = lds_y[oq + 16 * c][f];
            #pragma unroll
            for (int r = 0; r < 4; ++r)
                #pragma unroll
                for (int c = 0; c < 4; ++c)
                    acc[r][c] += wv[r].x * yv[c].x + wv[r].y * yv[c].y;
        }
        __syncthreads();
    }
    #pragma unroll
    for (int c = 0; c < 4; ++c) {
        const int o = oq + 16 * c;
        const float4 v = make_float4(acc[0][c], acc[1][c], acc[2][c], acc[3][c]);
        *(float4*)(out + ((size_t)(bh * 64 + o)) * 4096 + tt * 64 + t0) = v;
    }
}

extern "C" void kernel_launch(void* const* d_in, const int* in_sizes, int n_in,
                              void* d_out, int out_size, void* d_ws, size_t ws_size,
                              hipStream_t stream) {
    const float* q  = (const float*)d_in[0];
    // d_in[1]=k, d_in[2]=v, d_in[3]=mask: unused by the reference forward.
    const float* wr = (const float*)d_in[4];
    const float* wi = (const float*)d_in[5];
    float* out = (float*)d_out;
    float* ws  = (float*)d_ws;   // needs 3,145,728 floats = 12 MB

    k_twiddle<<<1024, 256, 0, stream>>>(ws);
    k_dft<<<256, 256, 0, stream>>>(q, ws);
    k_mix<<<128, 256, 0, stream>>>(wr, wi, ws);
    k_inv<<<8192, 256, 0, stream>>>(out, ws);
}

// Round 2
// 452.810 us; speedup vs baseline: 2.0259x; 2.0259x over previous
//
#include <hip/hip_runtime.h>
#include <math.h>

// SpectralConv1d via three GEMMs, bf16 MFMA for the two big ones.
//   Stage 1 (k_dft): Xhat[fh][e] = sum_t TW1[fh][t] * q[t][e], fh<128
//                    rows 0..63 = cos(2pi f t/L) (Xr), rows 64..127 = -sin (Xi).
//                    K=4096 split 4 ways -> fp32 partials Xp[kc][bh][fh][e].
//   Stage 2 (k_mix): reduce partials + complex mode mix with W (fp32),
//                    emit Yhat bf16 pre-shuffled into stage-3 A-fragment order.
//   Stage 3 (k_inv): out[o][t] = sum_fh Yhat[o][fh] * TW2[fh][t],
//                    fh=2f -> sc*cos, fh=2f+1 -> -sc*sin, sc=(f?2:1)/4096.
// Both twiddle tables are generated per-launch directly in MFMA fragment order
// (A: m=lane&15, k=(lane>>4)*8+j ; B: n=lane&15, same k), so operand loads are
// single coalesced b128 global loads (L2/L3-resident) — no LDS in the GEMMs.
//
// ws layout (float units): total 5,242,880 floats = 21 MB.
#define TW1_OFF 0          // bf16[512K]: stage-1 A, frag order [tchunk<128][mt<8][lane][j]
#define TW2_OFF 262144     // bf16[512K]: stage-3 B, frag order [tc<32][nt8<8][ks<4][lane][j]
#define YH_OFF  524288     // bf16[1M] : stage-3 A, frag order [bh][mt<4][ks<4][lane][j]
#define XP_OFF  1048576    // float[4M]: stage-1 partial C [kc<4][bh<128][fh<128][e<64]

typedef short s16x8 __attribute__((ext_vector_type(8)));   // 8 bf16 in 4 VGPRs
typedef float f32x4 __attribute__((ext_vector_type(4)));

__device__ inline unsigned short f2bf(float x) {   // fp32 -> bf16 bits, RNE
    union { float f; unsigned int u; } v; v.f = x;
    return (unsigned short)((v.u + 0x7fffu + ((v.u >> 16) & 1u)) >> 16);
}

// ---------------- twiddle tables, fragment order, bf16 ----------------
__global__ __launch_bounds__(256) void k_tw(float* __restrict__ ws) {
    const int i = blockIdx.x * 256 + threadIdx.x;    // 0..524287
    const float C = 1.53398078788564123e-3f;         // 2*pi/4096
    {   // TW1: fh = mt*16 + (lane&15); t = tch*32 + (lane>>4)*8 + j
        const int j = i & 7, lane = (i >> 3) & 63, mt = (i >> 9) & 7, tch = i >> 12;
        const int fh = mt * 16 + (lane & 15);
        const int t  = tch * 32 + ((lane >> 4) << 3) + j;
        const int f  = fh & 63;
        float s, c;
        sincosf((float)((f * t) & 4095) * C, &s, &c);
        ((unsigned short*)(ws + TW1_OFF))[i] = f2bf(fh < 64 ? c : -s);
    }
    {   // TW2: t = tc*128 + nt*16 + (lane&15); fh = ks*32 + (lane>>4)*8 + j
        const int j = i & 7, lane = (i >> 3) & 63, ks = (i >> 9) & 3, nt = (i >> 11) & 7, tc = i >> 14;
        const int t  = tc * 128 + nt * 16 + (lane & 15);
        const int fh = ks * 32 + ((lane >> 4) << 3) + j;
        const int f  = fh >> 1;
        float s, c;
        sincosf((float)((f * t) & 4095) * C, &s, &c);
        const float sc = (f ? 2.0f : 1.0f) * (1.0f / 4096.0f);
        ((unsigned short*)(ws + TW2_OFF))[i] = f2bf((fh & 1) ? -sc * s : sc * c);
    }
}

// ---------------- stage 1: truncated DFT, bf16 MFMA ----------------
// grid 512 = kc*128 + bh. Block 256 = 4 waves: (wm,wn)=(w>>1,w&1).
// Wave tile M=64 (mt 4) x N=32 (nt 2), K=1024 per block in 64-chunks.
__global__ __launch_bounds__(256) void k_dft(const float* __restrict__ q,
                                             float* __restrict__ ws) {
    const int bid = blockIdx.x;
    const int kc = bid >> 7, bh = bid & 127;
    const int b = bh >> 3, h = bh & 7;
    const int tid = threadIdx.x;
    const int lane = tid & 63, w = tid >> 6;
    const int wm = w >> 1, wn = w & 1;
    const int l15 = lane & 15, qd = lane >> 4;

    const s16x8* __restrict__ tw1 = (const s16x8*)(ws + TW1_OFF);
    const float* __restrict__ qb = q + (size_t)b * 2097152 + h * 64;

    f32x4 acc[4][2];
#pragma unroll
    for (int mt = 0; mt < 4; ++mt)
#pragma unroll
        for (int nt = 0; nt < 2; ++nt)
            acc[mt][nt] = (f32x4){0.f, 0.f, 0.f, 0.f};

    for (int it = 0; it < 16; ++it) {
        const int tch0 = kc * 32 + it * 2;
        s16x8 afr[4][2];
#pragma unroll
        for (int mt = 0; mt < 4; ++mt)
#pragma unroll
            for (int ks = 0; ks < 2; ++ks)
                afr[mt][ks] = tw1[(size_t)((tch0 + ks) * 8 + wm * 4 + mt) * 64 + lane];

        const int tbase = kc * 1024 + it * 64;
        s16x8 bfr[2][2];
#pragma unroll
        for (int nt = 0; nt < 2; ++nt) {
            const int e = wn * 32 + nt * 16 + l15;
#pragma unroll
            for (int ks = 0; ks < 2; ++ks) {
                const float* qp = qb + (size_t)(tbase + ks * 32 + qd * 8) * 512 + e;
#pragma unroll
                for (int j = 0; j < 8; ++j)
                    bfr[nt][ks][j] = (short)f2bf(qp[(size_t)j * 512]);
            }
        }
#pragma unroll
        for (int ks = 0; ks < 2; ++ks)
#pragma unroll
            for (int mt = 0; mt < 4; ++mt)
#pragma unroll
                for (int nt = 0; nt < 2; ++nt)
                    acc[mt][nt] = __builtin_amdgcn_mfma_f32_16x16x32_bf16(
                        afr[mt][ks], bfr[nt][ks], acc[mt][nt], 0, 0, 0);
    }
    // C layout: row m = (lane>>4)*4+reg (verified m89/m91), col n = lane&15.
    float* xp = ws + XP_OFF + (size_t)(kc * 128 + bh) * 8192;
#pragma unroll
    for (int mt = 0; mt < 4; ++mt)
#pragma unroll
        for (int nt = 0; nt < 2; ++nt) {
            const int e = wn * 32 + nt * 16 + l15;
#pragma unroll
            for (int r = 0; r < 4; ++r) {
                const int fh = (wm * 4 + mt) * 16 + qd * 4 + r;
                xp[fh * 64 + e] = acc[mt][nt][r];
            }
        }
}

// ---------------- stage 2: reduce partials + mode mix (fp32) ----------------
// grid 256 = bh*2 + fhalf. Thread: f = f0 + (tid&31), og = tid>>5, o = og+8*oo.
__global__ __launch_bounds__(256) void k_mix(const float* __restrict__ wr_g,
                                             const float* __restrict__ wi_g,
                                             float* __restrict__ ws) {
    __shared__ float lds_x[64][69];   // Xr at [e][fl], Xi at [e][fl+34]; 69 breaks banks
    const int bid = blockIdx.x;
    const int bh = bid >> 1, f0 = (bid & 1) * 32;
    const int h = bh & 7;
    const int tid = threadIdx.x;
    const float* xp = ws + XP_OFF;
#pragma unroll
    for (int p = 0; p < 2; ++p)
#pragma unroll
        for (int k2 = 0; k2 < 8; ++k2) {
            const int idx = tid + k2 * 256;          // 0..2047 = 32 rows x 64 e
            const int fl = idx >> 6, e = idx & 63;
            const int row = p * 64 + f0 + fl;
            float s = 0.f;
#pragma unroll
            for (int kc = 0; kc < 4; ++kc)
                s += xp[(size_t)(kc * 128 + bh) * 8192 + row * 64 + e];
            lds_x[e][fl + p * 34] = s;
        }
    __syncthreads();
    const int fl = tid & 31, og = tid >> 5;
    const int f = f0 + fl;
    float yr[8], yi[8];
#pragma unroll
    for (int oo = 0; oo < 8; ++oo) { yr[oo] = 0.f; yi[oo] = 0.f; }
    const float* wrp = wr_g + (size_t)h * 262144 + og * 64 + f;
    const float* wip = wi_g + (size_t)h * 262144 + og * 64 + f;
    for (int e = 0; e < 64; ++e) {
        const float xr = lds_x[e][fl], xi = lds_x[e][fl + 34];
        const float* wre = wrp + (size_t)e * 4096;
        const float* wie = wip + (size_t)e * 4096;
#pragma unroll
        for (int oo = 0; oo < 8; ++oo) {        // o = og + 8*oo -> stride 512 floats
            const float wr = wre[oo * 512];
            const float wi = wie[oo * 512];
            yr[oo] += xr * wr - xi * wi;
            yi[oo] += xr * wi + xi * wr;
        }
    }
    // scatter-write Yhat in stage-3 A fragment order
    unsigned short* yh = (unsigned short*)(ws + YH_OFF);
#pragma unroll
    for (int oo = 0; oo < 8; ++oo) {
        const int o = og + 8 * oo;
        const int mt = o >> 4, ol = o & 15;
#pragma unroll
        for (int ri = 0; ri < 2; ++ri) {
            const int fh = 2 * f + ri;
            const float v = ri ? yi[oo] : yr[oo];
            yh[((size_t)((bh * 4 + mt) * 4 + (fh >> 5)) * 64 + ((fh >> 3) & 3) * 16 + ol) * 8 + (fh & 7)] = f2bf(v);
        }
    }
}

// ---------------- stage 3: truncated inverse, bf16 MFMA ----------------
// grid 4096 = tc*128 + bh. Wave w: t-range 32, full M=64, K=128 (4 k-steps).
__global__ __launch_bounds__(256) void k_inv(float* __restrict__ out,
                                             const float* __restrict__ ws) {
    const int bid = blockIdx.x;
    const int tc = bid >> 7, bh = bid & 127;
    const int tid = threadIdx.x, lane = tid & 63, w = tid >> 6;
    const int l15 = lane & 15, qd = lane >> 4;
    const s16x8* __restrict__ ya = (const s16x8*)(ws + YH_OFF);
    const s16x8* __restrict__ tb = (const s16x8*)(ws + TW2_OFF);
    f32x4 acc[4][2];
#pragma unroll
    for (int mt = 0; mt < 4; ++mt)
#pragma unroll
        for (int nt = 0; nt < 2; ++nt)
            acc[mt][nt] = (f32x4){0.f, 0.f, 0.f, 0.f};
#pragma unroll
    for (int ks = 0; ks < 4; ++ks) {
        s16x8 af[4], bfv[2];
#pragma unroll
        for (int mt = 0; mt < 4; ++mt)
            af[mt] = ya[(size_t)((bh * 4 + mt) * 4 + ks) * 64 + lane];
#pragma unroll
        for (int nt = 0; nt < 2; ++nt)
            bfv[nt] = tb[(size_t)((tc * 8 + w * 2 + nt) * 4 + ks) * 64 + lane];
#pragma unroll
        for (int mt = 0; mt < 4; ++mt)
#pragma unroll
            for (int nt = 0; nt < 2; ++nt)
                acc[mt][nt] = __builtin_amdgcn_mfma_f32_16x16x32_bf16(
                    af[mt], bfv[nt], acc[mt][nt], 0, 0, 0);
    }
    float* ob = out + (size_t)bh * 262144 + tc * 128 + w * 32;
#pragma unroll
    for (int mt = 0; mt < 4; ++mt)
#pragma unroll
        for (int nt = 0; nt < 2; ++nt)
#pragma unroll
            for (int r = 0; r < 4; ++r) {
                const int o = mt * 16 + qd * 4 + r;
                ob[(size_t)o * 4096 + nt * 16 + l15] = acc[mt][nt][r];
            }
}

extern "C" void kernel_launch(void* const* d_in, const int* in_sizes, int n_in,
                              void* d_out, int out_size, void* d_ws, size_t ws_size,
                              hipStream_t stream) {
    const float* q  = (const float*)d_in[0];
    // d_in[1]=k, d_in[2]=v, d_in[3]=mask: unused by the reference forward.
    const float* wr = (const float*)d_in[4];
    const float* wi = (const float*)d_in[5];
    float* out = (float*)d_out;
    float* ws  = (float*)d_ws;    // needs 21 MB

    k_tw <<<2048, 256, 0, stream>>>(ws);
    k_dft<<<512,  256, 0, stream>>>(q, ws);
    k_mix<<<256,  256, 0, stream>>>(wr, wi, ws);
    k_inv<<<4096, 256, 0, stream>>>(out, ws);
}